// Round 19
// baseline (33.149 us; speedup 1.0000x reference)
//
#include <hip/hip_runtime.h>
#include <math.h>

#define NT 64
#define L_LEN 720
#define NCHUNKS 180            // float4 chunks per row
#define NROWS (64 * 321)       // 20544

#define LOG2E 1.4426950408889634f
#define LN2   0.6931471805599453f

typedef float f32x2 __attribute__((ext_vector_type(2)));

__device__ __forceinline__ f32x2 pkfma(f32x2 a, f32x2 b, f32x2 c) {
    return __builtin_elementwise_fma(a, b, c);   // -> v_pk_fma_f32
}

// ---- DPP wave reductions: pure VALU pipe, no LDS, no lgkmcnt stalls ----
template<int CTRL, int RM>
__device__ __forceinline__ float dpp_add(float x) {
    int t = __builtin_amdgcn_update_dpp(0, __float_as_int(x), CTRL, RM, 0xf, true);
    return x + __int_as_float(t);
}

__device__ __forceinline__ float wave_sum64(float x) {
    x = dpp_add<0x111, 0xf>(x);   // row_shr:1
    x = dpp_add<0x112, 0xf>(x);   // row_shr:2
    x = dpp_add<0x114, 0xf>(x);   // row_shr:4
    x = dpp_add<0x118, 0xf>(x);   // row_shr:8
    x = dpp_add<0x142, 0xa>(x);   // row_bcast:15 -> rows 1,3
    x = dpp_add<0x143, 0xc>(x);   // row_bcast:31 -> rows 2,3 ; lane63 = total
    return __int_as_float(__builtin_amdgcn_readlane(__float_as_int(x), 63));
}

__device__ __forceinline__ float half_sum32(float x) {
    x = dpp_add<0x111, 0xf>(x);
    x = dpp_add<0x112, 0xf>(x);
    x = dpp_add<0x114, 0xf>(x);
    x = dpp_add<0x118, 0xf>(x);
    x = dpp_add<0x142, 0xa>(x);   // lane31 = sum lanes 0..31
    return __int_as_float(__builtin_amdgcn_readlane(__float_as_int(x), 31));
}

__global__ __launch_bounds__(NT, 4) void trend_kernel(
    const float* __restrict__ x,
    const float* __restrict__ cw0, const float* __restrict__ cb0,
    const float* __restrict__ cw1, const float* __restrict__ cb1,
    const float* __restrict__ cw2, const float* __restrict__ cb2,
    const float* __restrict__ cw3, const float* __restrict__ cb3,
    const float* __restrict__ W1, const float* __restrict__ b1,
    const float* __restrict__ W2, const float* __restrict__ b2,
    float* __restrict__ out)
{
    // DENSE-TRANSACTION layout: lane owns float4 chunks {lane, lane+60,
    // lane+120} (3 segments of 4 elements). Every global load/store is
    // lane-contiguous (16B x 60 lanes = 960B dense) -> ~16 cache lines per
    // instruction instead of 48 for the old 48B-stride pattern. Compute
    // (packed conv, fu kept, DPP tail) identical to R18.
    const int lane = threadIdx.x;            // 0..63
    const int row  = blockIdx.x;

    const float*  __restrict__ xr = x + (size_t)row * L_LEN;
    const float4* __restrict__ xc = (const float4*)xr;

    const int  ll     = (lane < 60) ? lane : 59;   // lanes 60..63 shadow 59
    const bool active = lane < 60;

    // ---- 9 dense chunk loads: segment q needs chunks (c-1, c, c+1), c = ll+60q
    float4 xq[3][3];
#pragma unroll
    for (int q = 0; q < 3; ++q) {
#pragma unroll
        for (int r = 0; r < 3; ++r) {
            int c = ll + 60 * q + r - 1;
            c = (c < 0) ? 0 : ((c > NCHUNKS - 1) ? (NCHUNKS - 1) : c);
            xq[q][r] = xc[c];
        }
    }

    // ---- MLP operand loads issued early (hide under conv)
    const int hidx = lane & 31;
    float w1r[4];
#pragma unroll
    for (int s = 0; s < 4; ++s) w1r[s] = W1[s * 32 + hidx];
    const float b1r = b1[hidx];
    const float4 w2v = ((const float4*)W2)[hidx];
    const float b20 = b2[0], b21 = b2[1], b22 = b2[2], b23 = b2[3];

    // ---- RAW conv weights: uniform addresses -> scalar loads (no VALU)
    const float* cws[4] = {cw0, cw1, cw2, cw3};
    const float* cbs[4] = {cb0, cb1, cb2, cb3};
    float w[4][9], bs[4];
#pragma unroll
    for (int s = 0; s < 4; ++s) {
        const int k = 3 + 2 * s;
        bs[s] = cbs[s][0];
#pragma unroll
        for (int t = 0; t < 9; ++t)
            w[s][t] = (t < k) ? cws[s][t] : 0.0f;
    }

    // ---- zero the row-edge halos (clamped loads filled them with data)
    if (lane == 0)  xq[0][0] = (float4){0.f, 0.f, 0.f, 0.f};
    if (lane == 59) xq[2][2] = (float4){0.f, 0.f, 0.f, 0.f};

    // pin the loaded quads: loaded exactly once, no remat/re-fetch
#pragma unroll
    for (int q = 0; q < 3; ++q)
#pragma unroll
        for (int r = 0; r < 3; ++r)
            asm volatile("" : "+v"(xq[q][r].x), "+v"(xq[q][r].y),
                              "+v"(xq[q][r].z), "+v"(xq[q][r].w));

    // ---- per-segment packed conv -> exp -> S,T accumulate; f kept in fu
    const f32x2 l2e = (f32x2){LOG2E, LOG2E};
    f32x2 fu[4][6];                 // [scale][2q + pairIdx]
    f32x2 Spk[4] = {{0.f,0.f},{0.f,0.f},{0.f,0.f},{0.f,0.f}};
    f32x2 Tpk[4] = {{0.f,0.f},{0.f,0.f},{0.f,0.f},{0.f,0.f}};

#pragma unroll
    for (int q = 0; q < 3; ++q) {
        // window xv[0..11] = elements 4c-4 .. 4c+7 (c = ll + 60q)
        const float xv[12] = {
            xq[q][0].x, xq[q][0].y, xq[q][0].z, xq[q][0].w,
            xq[q][1].x, xq[q][1].y, xq[q][1].z, xq[q][1].w,
            xq[q][2].x, xq[q][2].y, xq[q][2].z, xq[q][2].w };

        // stride-1 pair views (even pairs map to load-aligned reg pairs)
        f32x2 pe[6], po[5];
#pragma unroll
        for (int i = 0; i < 6; ++i) pe[i] = (f32x2){xv[2 * i], xv[2 * i + 1]};
#pragma unroll
        for (int i = 0; i < 5; ++i) po[i] = (f32x2){xv[2 * i + 1], xv[2 * i + 2]};

#pragma unroll
        for (int pi = 0; pi < 2; ++pi) {       // outputs (2pi, 2pi+1)
            const int j0 = 2 * pi;
#pragma unroll
            for (int s = 0; s < 4; ++s) {
                const int k = 3 + 2 * s;
                const int off = 3 - s;          // 4 - k/2
                f32x2 f = (f32x2){bs[s], bs[s]};
#pragma unroll
                for (int t = 0; t < k; ++t) {
                    const int i = j0 + off + t;     // 0..10
                    const f32x2 pv = (i & 1) ? po[i >> 1] : pe[i >> 1];
                    f = pkfma((f32x2){w[s][t], w[s][t]}, pv, f);
                }
                fu[s][2 * q + pi] = f;
                f32x2 u = f * l2e;
                f32x2 ev;
                ev.x = __builtin_amdgcn_exp2f(u.x);
                ev.y = __builtin_amdgcn_exp2f(u.y);
                Spk[s] += ev;
                Tpk[s] = pkfma(f, ev, Tpk[s]);  // natural units
            }
        }
    }

    // pin fu: conv computed exactly once (no remat through the tail)
#pragma unroll
    for (int s = 0; s < 4; ++s)
#pragma unroll
        for (int j = 0; j < 6; ++j)
            asm volatile("" : "+v"(fu[s][j].x), "+v"(fu[s][j].y));

    // combine packed halves; mask lanes 60..63 (duplicates of 59)
    float S[4], Tn[4];
#pragma unroll
    for (int s = 0; s < 4; ++s) {
        S[s]  = active ? (Spk[s].x + Spk[s].y) : 0.0f;
        Tn[s] = active ? (Tpk[s].x + Tpk[s].y) : 0.0f;
    }

    // wave totals via DPP; entropy = ln2*log2(S) - Tn/S
    float ent[4];
#pragma unroll
    for (int s = 0; s < 4; ++s) {
        float Sg = wave_sum64(S[s]);
        float Tg = wave_sum64(Tn[s]);
        ent[s] = fmaf(LN2, __builtin_amdgcn_logf(Sg),
                      -Tg * __builtin_amdgcn_rcpf(Sg));
    }

    // MLP: hidden unit per lane (mod 32); logits via DPP 32-lane sums
    float h = b1r;
#pragma unroll
    for (int s = 0; s < 4; ++s) h = fmaf(ent[s], w1r[s], h);
    h = fmaxf(h, 0.0f);

    float lg0 = half_sum32(h * w2v.x) + b20;
    float lg1 = half_sum32(h * w2v.y) + b21;
    float lg2 = half_sum32(h * w2v.z) + b22;
    float lg3 = half_sum32(h * w2v.w) + b23;

    // softmax (wave-uniform); weights apply to natural f directly
    float m = fmaxf(fmaxf(lg0, lg1), fmaxf(lg2, lg3));
    float e0w = __expf(lg0 - m), e1w = __expf(lg1 - m);
    float e2w = __expf(lg2 - m), e3w = __expf(lg3 - m);
    float inv = 1.0f / (e0w + e1w + e2w + e3w);
    const float wg0 = e0w * inv, wg1 = e1w * inv;
    const float wg2 = e2w * inv, wg3 = e3w * inv;

    // ---- output: mix kept f pairs, DENSE float4 stores (chunk ll + 60q)
    if (active) {
        float4* __restrict__ oc = (float4*)(out + (size_t)row * L_LEN);
#pragma unroll
        for (int q = 0; q < 3; ++q) {
            f32x2 o0 = (f32x2){wg0, wg0} * fu[0][2 * q];
            o0 = pkfma((f32x2){wg1, wg1}, fu[1][2 * q], o0);
            o0 = pkfma((f32x2){wg2, wg2}, fu[2][2 * q], o0);
            o0 = pkfma((f32x2){wg3, wg3}, fu[3][2 * q], o0);
            f32x2 o1 = (f32x2){wg0, wg0} * fu[0][2 * q + 1];
            o1 = pkfma((f32x2){wg1, wg1}, fu[1][2 * q + 1], o1);
            o1 = pkfma((f32x2){wg2, wg2}, fu[2][2 * q + 1], o1);
            o1 = pkfma((f32x2){wg3, wg3}, fu[3][2 * q + 1], o1);
            float4 v = {o0.x, o0.y, o1.x, o1.y};
            oc[lane + 60 * q] = v;
        }
    }
}

extern "C" void kernel_launch(void* const* d_in, const int* in_sizes, int n_in,
                              void* d_out, int out_size, void* d_ws, size_t ws_size,
                              hipStream_t stream) {
    const float* xp  = (const float*)d_in[0];
    const float* cw0 = (const float*)d_in[1];
    const float* cb0 = (const float*)d_in[2];
    const float* cw1 = (const float*)d_in[3];
    const float* cb1 = (const float*)d_in[4];
    const float* cw2 = (const float*)d_in[5];
    const float* cb2 = (const float*)d_in[6];
    const float* cw3 = (const float*)d_in[7];
    const float* cb3 = (const float*)d_in[8];
    const float* W1  = (const float*)d_in[9];
    const float* b1  = (const float*)d_in[10];
    const float* W2  = (const float*)d_in[11];
    const float* b2  = (const float*)d_in[12];
    float* outp = (float*)d_out;

    trend_kernel<<<NROWS, NT, 0, stream>>>(xp, cw0, cb0, cw1, cb1, cw2, cb2,
                                           cw3, cb3, W1, b1, W2, b2, outp);
}